// Round 8
// baseline (317.111 us; speedup 1.0000x reference)
//
#include <hip/hip_runtime.h>
#include <hip/hip_bf16.h>

#define DG 16384
#define NNZ 262144
#define BB 128

typedef __attribute__((ext_vector_type(8))) short bf16x8;
typedef __attribute__((ext_vector_type(8))) unsigned short us8;
typedef __attribute__((ext_vector_type(4))) float f32x4;
typedef __attribute__((ext_vector_type(4))) unsigned short us4;
typedef __attribute__((ext_vector_type(2))) float f32x2;

// ---- workspace layout (bytes) ----
#define WS_ROWPTR 0            // 16385 ints
#define WS_XIN16  66048        // 128*16384 bf16
#define WS_T      4260352      // 6 fp32 planes of 16384*128
#define WS_XPOOL  54592000     // 128*65536 bf16
#define WS_XB0    71369216     // bf16 shadow plane A
#define WS_XB1    75563520     // bf16 shadow plane B
#define WS_XNN1B  79757824     // 128*512 bf16
#define WS_DEC2   79888896     // 128*512 bf16
#define WS_XNN2   80019968     // 128*256 fp32
#define WS_HIDB   80151040     // 128*512 bf16
#define WS_N1     80282112     // 256*4
#define WS_TAIL   80283136     // 128*4
#define WS_PNN1   81000448     // 64 planes * 256KB = 16.8MB
#define WS_PFC1   97777664     // 256 planes * 256KB = 67.1MB (ends ~164.9MB)

__device__ __forceinline__ unsigned short f2bf(float f) {
  __hip_bfloat16 h = __float2bfloat16(f);
  return __builtin_bit_cast(unsigned short, h);
}
__device__ __forceinline__ float bflo(unsigned u) {
  return __builtin_bit_cast(float, u << 16);
}
__device__ __forceinline__ float bfhi(unsigned u) {
  return __builtin_bit_cast(float, u & 0xffff0000u);
}

// ================= fused setup: g4 | nn14 | prep | transpose =================
__device__ void prep_dev(const float* __restrict__ x_in, const int* __restrict__ rows,
                         int* __restrict__ rowptr, unsigned short* __restrict__ xin16,
                         int bid) {
  int idx = bid * 256 + threadIdx.x;
  if (idx <= DG) {
    int lo = 0, hi = NNZ;
    while (lo < hi) { int mid = (lo + hi) >> 1; if (rows[mid] < idx) lo = mid + 1; else hi = mid; }
    rowptr[idx] = lo;
  }
  f32x4 v = ((const f32x4*)x_in)[idx];
  us4 o; o[0] = f2bf(v[0]); o[1] = f2bf(v[1]); o[2] = f2bf(v[2]); o[3] = f2bf(v[3]);
  ((us4*)xin16)[idx] = o;
}

__device__ void transpose_dev(const float* __restrict__ x_in, float* __restrict__ T0,
                              unsigned short* __restrict__ Xb0, int id) {
  __shared__ float tl[32][33];
  int bx = id & 511, by = id >> 9;
  int v0 = bx * 32, b0 = by * 32;
  int tx = threadIdx.x & 31, ty0 = threadIdx.x >> 5;
  #pragma unroll
  for (int j = 0; j < 4; ++j) {
    int ty = ty0 + j * 8;
    tl[ty][tx] = x_in[(size_t)(b0 + ty) * DG + v0 + tx];
  }
  __syncthreads();
  #pragma unroll
  for (int j = 0; j < 4; ++j) {
    int ty = ty0 + j * 8;
    float v = tl[tx][ty];
    size_t o = (size_t)(v0 + ty) * BB + b0 + tx;
    T0[o] = v;
    Xb0[o] = f2bf(v);
  }
}

__device__ void dot4_dev(const float* __restrict__ x, const float* __restrict__ W,
                         const float* __restrict__ bias, float* __restrict__ out,
                         int K, int id) {
  int w = threadIdx.x >> 6, lane = threadIdx.x & 63;
  int o = id * 4 + w;
  float a = 0.f;
  for (int i = lane; i < K; i += 64) a += x[i] * W[(size_t)o * K + i];
  #pragma unroll
  for (int s = 32; s > 0; s >>= 1) a += __shfl_down(a, s);
  if (lane == 0) out[o] = fmaxf(a + bias[o], 0.f);
}

__device__ void g4_dev(const float* __restrict__ xe_g, const float* __restrict__ Lmg_g,
                       const float* __restrict__ W4, const float* __restrict__ b4,
                       const float* __restrict__ Wg1, const float* __restrict__ bg1,
                       const float* __restrict__ Wg2, const float* __restrict__ bg2,
                       float* __restrict__ tail) {
  __shared__ float Lm[100], Tg[4][640], xc[320], xg96[96], h1[128];
  int t = threadIdx.x;
  for (int i = t; i < 640; i += 256) Tg[0][i] = xe_g[i];
  for (int i = t; i < 100; i += 256) Lm[i] = Lmg_g[i];
  __syncthreads();
  for (int i = t; i < 640; i += 256) {
    int v = i >> 6, f = i & 63; float s = 0.f;
    #pragma unroll
    for (int u = 0; u < 10; ++u) s += Lm[v * 10 + u] * Tg[0][u * 64 + f];
    Tg[1][i] = s;
  }
  __syncthreads();
  for (int kk = 2; kk < 4; ++kk) {
    for (int i = t; i < 640; i += 256) {
      int v = i >> 6, f = i & 63; float s = 0.f;
      #pragma unroll
      for (int u = 0; u < 10; ++u) s += Lm[v * 10 + u] * Tg[kk - 1][u * 64 + f];
      Tg[kk][i] = 2.f * s - Tg[kk - 2][i];
    }
    __syncthreads();
  }
  for (int i = t; i < 320; i += 256) {
    int v = i >> 5, fo = i & 31; float s = b4[fo];
    for (int fin = 0; fin < 64; ++fin)
      #pragma unroll
      for (int k = 0; k < 4; ++k) s += Tg[k][v * 64 + fin] * W4[fo * 256 + fin * 4 + k];
    xc[i] = fmaxf(s, 0.f);
  }
  __syncthreads();
  for (int i = t; i < 96; i += 256) {
    int g = i >> 5, fo = i & 31;
    xg96[i] = fmaxf(fmaxf(xc[(3 * g) * 32 + fo], xc[(3 * g + 1) * 32 + fo]),
                    xc[(3 * g + 2) * 32 + fo]);
  }
  __syncthreads();
  for (int o = t; o < 128; o += 256) {
    float s = bg1[o];
    for (int i2 = 0; i2 < 96; ++i2) s += xg96[i2] * Wg1[o * 96 + i2];
    h1[o] = fmaxf(s, 0.f);
  }
  __syncthreads();
  for (int o = t; o < 64; o += 256) {
    float s = bg2[o];
    for (int i2 = 0; i2 < 128; ++i2) s += h1[i2] * Wg2[o * 128 + i2];
    tail[o] = fmaxf(s, 0.f);
  }
}

__global__ __launch_bounds__(256) void setup_kernel(
    const float* __restrict__ x_in, const int* __restrict__ rows,
    int* __restrict__ rowptr, unsigned short* __restrict__ xin16,
    float* __restrict__ T0, unsigned short* __restrict__ Xb0,
    const float* __restrict__ x_embed,
    const float* __restrict__ nn14_W, const float* __restrict__ nn14_b,
    float* __restrict__ n1,
    const float* __restrict__ Lmg, const float* __restrict__ W4,
    const float* __restrict__ b4, const float* __restrict__ Wg1,
    const float* __restrict__ bg1, const float* __restrict__ Wg2,
    const float* __restrict__ bg2, float* __restrict__ tail) {
  int bid = blockIdx.x;
  if (bid < 1) g4_dev(x_embed, Lmg, W4, b4, Wg1, bg1, Wg2, bg2, tail);
  else if (bid < 65) dot4_dev(x_embed, nn14_W, nn14_b, n1, 640, bid - 1);
  else if (bid < 2113) prep_dev(x_in, rows, rowptr, xin16, bid - 65);
  else transpose_dev(x_in, T0, Xb0, bid - 2113);
}

// ====== SpMM: 1 wave/row, ushort2 gathers, Chebyshev update (R4-proven) ======
__global__ __launch_bounds__(256) void spmm3(
    const int* __restrict__ rowptr, const int* __restrict__ cols,
    const float* __restrict__ vals, const unsigned* __restrict__ X2,
    const float* __restrict__ Tprev, float* __restrict__ Tout,
    unsigned* __restrict__ Xbout, float scale) {
  int r = blockIdx.x * 4 + (threadIdx.x >> 6);
  int lane = threadIdx.x & 63;
  int e0 = rowptr[r], e1 = rowptr[r + 1];
  float a00 = 0.f, a01 = 0.f, a10 = 0.f, a11 = 0.f;
  int e = e0;
  for (; e + 4 <= e1; e += 4) {
    int c0 = cols[e], c1 = cols[e + 1], c2 = cols[e + 2], c3 = cols[e + 3];
    float v0 = vals[e], v1 = vals[e + 1], v2 = vals[e + 2], v3 = vals[e + 3];
    unsigned x0 = X2[c0 * 64 + lane], x1 = X2[c1 * 64 + lane];
    unsigned x2 = X2[c2 * 64 + lane], x3 = X2[c3 * 64 + lane];
    a00 += v0 * bflo(x0); a10 += v0 * bfhi(x0);
    a01 += v1 * bflo(x1); a11 += v1 * bfhi(x1);
    a00 += v2 * bflo(x2); a10 += v2 * bfhi(x2);
    a01 += v3 * bflo(x3); a11 += v3 * bfhi(x3);
  }
  for (; e < e1; ++e) {
    float v = vals[e]; unsigned x = X2[cols[e] * 64 + lane];
    a00 += v * bflo(x); a10 += v * bfhi(x);
  }
  float s0 = scale * (a00 + a01), s1 = scale * (a10 + a11);
  size_t o = (size_t)r * BB + lane * 2;
  if (Tprev) { f32x2 p = *(const f32x2*)(Tprev + o); s0 -= p[0]; s1 -= p[1]; }
  *(f32x2*)(Tout + o) = (f32x2){s0, s1};
  Xbout[(size_t)r * 64 + lane] = (unsigned)f2bf(s0) | ((unsigned)f2bf(s1) << 16);
}

// ====== combine + maxpool (+ nn24 piggyback) ======
__device__ void combine_dev(const float* __restrict__ Tbase, const float* __restrict__ W,
                            const float* __restrict__ bias, unsigned short* __restrict__ xpool,
                            int vp) {
  __shared__ float tile[6][8][128];
  __shared__ float Wl[192];
  __shared__ float bl[32];
  for (int i = threadIdx.x; i < 192; i += 256) Wl[i] = W[i];
  if (threadIdx.x < 32) bl[threadIdx.x] = bias[threadIdx.x];
  for (int i = threadIdx.x; i < 6144; i += 256) {
    int k = i >> 10, rem = i & 1023, j = rem >> 7, b = rem & 127;
    tile[k][j][b] = Tbase[(size_t)k * 2097152 + (size_t)(vp * 8 + j) * BB + b];
  }
  __syncthreads();
  for (int p = threadIdx.x; p < 4096; p += 256) {
    int b = p >> 5, f = p & 31;
    float m = -1e30f;
    #pragma unroll
    for (int j = 0; j < 8; ++j) {
      float s = bl[f];
      #pragma unroll
      for (int k = 0; k < 6; ++k) s += tile[k][j][b] * Wl[f * 6 + k];
      m = fmaxf(m, s);
    }
    m = fmaxf(m, 0.f);
    xpool[(size_t)b * 65536 + vp * 32 + f] = f2bf(m);
  }
}

__global__ __launch_bounds__(256) void combine_nn24(
    const float* __restrict__ Tbase, const float* __restrict__ W,
    const float* __restrict__ bias, unsigned short* __restrict__ xpool,
    const float* __restrict__ n1, const float* __restrict__ nn24_W,
    const float* __restrict__ nn24_b, float* __restrict__ tail64) {
  int bid = blockIdx.x;
  if (bid < 2048) combine_dev(Tbase, W, bias, xpool, bid);
  else dot4_dev(n1, nn24_W, nn24_b, tail64, 256, bid - 2048);
}

// ====== LDS-staged MFMA GEMM core (R4-style serialized staging, no reg-prefetch) ======
template<int NT, int MT>
__device__ void gemm_core4(
    unsigned short* __restrict__ Alds,       // [MT*16 * 64]
    unsigned short* __restrict__ Wlds,       // [NT*64 * 64]
    const unsigned short* __restrict__ A, const float* __restrict__ W,
    float* __restrict__ outP, unsigned short* __restrict__ outB,
    const float* __restrict__ bias, int K, int N, int Kchunk,
    int bx, int by, int row0, int relu, int partial) {
  const int LA = MT / 2;        // us8 loads per thread for A tile (MT*16 rows x 64k)
  const int LW = NT * 4;        // f32x4 loads per thread for W tile (NT*64 rows x 64k)
  int t = threadIdx.x, w = t >> 6, lane = t & 63, lr = lane & 15, lg = lane >> 4;
  int n0 = bx * NT * 64;
  int kbeg = by * Kchunk;
  f32x4 acc[MT][NT];
  #pragma unroll
  for (int mt = 0; mt < MT; ++mt)
    #pragma unroll
    for (int nt = 0; nt < NT; ++nt) acc[mt][nt] = (f32x4){0.f, 0.f, 0.f, 0.f};
  int rowA[LA], kkA[LA], rowW[LW], kkW[LW];
  #pragma unroll
  for (int j = 0; j < LA; ++j) { int idx = j * 256 + t; rowA[j] = idx >> 3; kkA[j] = (idx & 7) * 8; }
  #pragma unroll
  for (int j = 0; j < LW; ++j) { int idx = j * 256 + t; rowW[j] = idx >> 4; kkW[j] = (idx & 15) * 4; }
  int stages = Kchunk >> 6;
  for (int s = 0; s < stages; ++s) {
    int k0 = kbeg + s * 64;
    __syncthreads();                         // previous stage's readers done
    #pragma unroll
    for (int j = 0; j < LA; ++j) {
      us8 v = *(const us8*)(A + (size_t)(row0 + rowA[j]) * K + k0 + kkA[j]);
      *(us8*)(Alds + rowA[j] * 64 + (kkA[j] ^ ((rowA[j] & 7) << 3))) = v;
    }
    #pragma unroll
    for (int j = 0; j < LW; ++j) {
      f32x4 v = *(const f32x4*)(W + (size_t)(n0 + rowW[j]) * K + k0 + kkW[j]);
      us4 o; o[0] = f2bf(v[0]); o[1] = f2bf(v[1]); o[2] = f2bf(v[2]); o[3] = f2bf(v[3]);
      *(us4*)(Wlds + rowW[j] * 64 + (kkW[j] ^ ((rowW[j] & 7) << 3))) = o;
    }
    __syncthreads();                         // LDS tile ready
    #pragma unroll
    for (int h = 0; h < 2; ++h) {
      int k32 = h * 32;
      bf16x8 bfr[NT];
      #pragma unroll
      for (int nt = 0; nt < NT; ++nt) {
        int wrow = w * NT * 16 + nt * 16 + lr;
        bfr[nt] = *(const bf16x8*)(Wlds + wrow * 64 + ((k32 + lg * 8) ^ ((wrow & 7) << 3)));
      }
      #pragma unroll
      for (int mt = 0; mt < MT; ++mt) {
        int arow = mt * 16 + lr;
        bf16x8 af = *(const bf16x8*)(Alds + arow * 64 + ((k32 + lg * 8) ^ ((arow & 7) << 3)));
        #pragma unroll
        for (int nt = 0; nt < NT; ++nt)
          acc[mt][nt] = __builtin_amdgcn_mfma_f32_16x16x32_bf16(af, bfr[nt], acc[mt][nt], 0, 0, 0);
      }
    }
  }
  if (partial) {
    float* P = outP + (size_t)by * 128 * (size_t)N;
    #pragma unroll
    for (int mt = 0; mt < MT; ++mt)
      #pragma unroll
      for (int nt = 0; nt < NT; ++nt) {
        int col = n0 + w * NT * 16 + nt * 16 + lr;
        #pragma unroll
        for (int r2 = 0; r2 < 4; ++r2) {
          int row = row0 + mt * 16 + lg * 4 + r2;
          P[(size_t)row * N + col] = acc[mt][nt][r2];
        }
      }
  } else {
    #pragma unroll
    for (int mt = 0; mt < MT; ++mt)
      #pragma unroll
      for (int nt = 0; nt < NT; ++nt) {
        int col = n0 + w * NT * 16 + nt * 16 + lr;
        float bc = bias[col];
        #pragma unroll
        for (int r2 = 0; r2 < 4; ++r2) {
          int row = row0 + mt * 16 + lg * 4 + r2;
          float v = acc[mt][nt][r2] + bc;
          if (relu) v = fmaxf(v, 0.f);
          if (outP) outP[(size_t)row * N + col] = v;
          if (outB) outB[(size_t)row * N + col] = f2bf(v);
        }
      }
  }
}

// ====== fused nn1+fc1 split-K partial gemm (Kchunk=256, XCD-swizzled) ======
__global__ __launch_bounds__(256) void gemm_partials(
    const unsigned short* __restrict__ xin16, const float* __restrict__ nn1_W,
    const unsigned short* __restrict__ xpool, const float* __restrict__ fc1_W,
    float* __restrict__ pnn1, float* __restrict__ pfc1) {
  __shared__ unsigned short Alds[128 * 64];
  __shared__ unsigned short Wlds[128 * 64];
  int nb = blockIdx.x;
  if (nb < 256) {
    // nn1: 64 K-planes x 4 col-tiles
    int xcd = nb & 7, q = nb >> 3, bx = q & 3, by = ((q >> 2) << 3) | xcd;
    gemm_core4<2, 8>(Alds, Wlds, xin16, nn1_W, pnn1, nullptr, nullptr,
                     16384, 512, 256, bx, by, 0, 0, 1);
  } else {
    // fc1: 256 K-planes x 4 col-tiles
    int b = nb - 256;
    int xcd = b & 7, q = b >> 3, bx = q & 3, by = ((q >> 2) << 3) | xcd;
    gemm_core4<2, 8>(Alds, Wlds, xpool, fc1_W, pfc1, nullptr, nullptr,
                     65536, 512, 256, bx, by, 0, 0, 1);
  }
}

// ====== fused split-K reduce: fc1 (S=256) + nn1 (S=64) ======
__global__ __launch_bounds__(256) void reduce_fused(
    const float* __restrict__ pfc1, const float* __restrict__ fc1_b,
    float* __restrict__ hidden, unsigned short* __restrict__ hidB,
    const float* __restrict__ pnn1, const float* __restrict__ nn1_b,
    unsigned short* __restrict__ xnn1b) {
  int b = blockIdx.x;
  if (b < 256) {
    int idx = b * 256 + threadIdx.x;
    float s = 0.f;
    for (int i = 0; i < 256; ++i) s += pfc1[(size_t)i * 65536 + idx];
    float v = fmaxf(s + fc1_b[idx & 511], 0.f);
    hidden[idx] = v;
    hidB[idx] = f2bf(v);
  } else {
    int idx = (b - 256) * 256 + threadIdx.x;
    float s = 0.f;
    for (int i = 0; i < 64; ++i) s += pnn1[(size_t)i * 65536 + idx];
    float v = fmaxf(s + nn1_b[idx & 511], 0.f);
    xnn1b[idx] = f2bf(v);
  }
}

// ====== fc2 + nn2 fused ======
__global__ __launch_bounds__(256) void fc2nn2_kernel(
    const unsigned short* __restrict__ hidB, const float* __restrict__ fc2_W,
    const float* __restrict__ fc2_b, unsigned short* __restrict__ dec2,
    const unsigned short* __restrict__ xnn1b, const float* __restrict__ nn2_W,
    const float* __restrict__ nn2_b, float* __restrict__ xnn2) {
  __shared__ unsigned short Alds[128 * 64];
  __shared__ unsigned short Wlds[64 * 64];
  int b = blockIdx.x;
  if (b < 8)
    gemm_core4<1, 8>(Alds, Wlds, hidB, fc2_W, nullptr, dec2, fc2_b,
                     512, 512, 512, b, 0, 0, 1, 0);
  else
    gemm_core4<1, 8>(Alds, Wlds, xnn1b, nn2_W, xnn2, nullptr, nn2_b,
                     512, 256, 512, b - 8, 0, 0, 1, 0);
}

// ====== fc3 (M-split x4) + fcsum head ======
__device__ void fcsum_dev(int id, const float* __restrict__ hidden,
                          const float* __restrict__ xnn2, const float* __restrict__ tail,
                          const float* __restrict__ Ws, const float* __restrict__ bs,
                          float* __restrict__ logp) {
  __shared__ float emb[4][896];
  int w = threadIdx.x >> 6, lane = threadIdx.x & 63;
  int b = id * 4 + w;
  for (int i = lane; i < 896; i += 64)
    emb[w][i] = (i < 512) ? hidden[b * 512 + i]
              : (i < 768) ? xnn2[b * 256 + (i - 512)]
                          : tail[i - 768];
  __syncthreads();
  float l[10];
  #pragma unroll
  for (int o = 0; o < 10; ++o) {
    float a = 0.f;
    for (int i = lane; i < 896; i += 64) a += emb[w][i] * Ws[o * 896 + i];
    #pragma unroll
    for (int s = 32; s > 0; s >>= 1) a += __shfl_down(a, s);
    l[o] = __shfl(a, 0) + bs[o];
  }
  float m = l[0];
  #pragma unroll
  for (int o = 1; o < 10; ++o) m = fmaxf(m, l[o]);
  float sum = 0.f;
  #pragma unroll
  for (int o = 0; o < 10; ++o) sum += expf(l[o] - m);
  float lse = m + logf(sum);
  #pragma unroll
  for (int o = 0; o < 10; ++o)
    if (lane == o) logp[b * 10 + o] = l[o] - lse;
}

__global__ __launch_bounds__(256) void fc3_head(
    const unsigned short* __restrict__ dec2, const float* __restrict__ fc3_W,
    const float* __restrict__ fc3_b, float* __restrict__ out0,
    const float* __restrict__ hidden, const float* __restrict__ xnn2,
    const float* __restrict__ tail, const float* __restrict__ fcsum_W,
    const float* __restrict__ fcsum_b, float* __restrict__ logp) {
  __shared__ unsigned short Alds[64 * 64];
  __shared__ unsigned short Wlds[64 * 64];
  int b = blockIdx.x;
  if (b < 1024) {
    int bx = b >> 2, my = b & 3;
    gemm_core4<1, 2>(Alds, Wlds, dec2, fc3_W, out0, nullptr, fc3_b,
                     512, 16384, 512, bx, 0, my * 32, 0, 0);
  } else {
    fcsum_dev(b - 1024, hidden, xnn2, tail, fcsum_W, fcsum_b, logp);
  }
}

extern "C" void kernel_launch(void* const* d_in, const int* in_sizes, int n_in,
                              void* d_out, int out_size, void* d_ws, size_t ws_size,
                              hipStream_t stream) {
  const float* x_in    = (const float*)d_in[0];
  const float* x_embed = (const float*)d_in[1];
  const int*   L_rows  = (const int*)d_in[3];
  const int*   L_cols  = (const int*)d_in[4];
  const float* L_vals  = (const float*)d_in[5];
  const float* L_mg    = (const float*)d_in[6];
  const float* cl1_W = (const float*)d_in[7],  *cl1_b = (const float*)d_in[8];
  const float* fc1_W = (const float*)d_in[9],  *fc1_b = (const float*)d_in[10];
  const float* fc2_W = (const float*)d_in[11], *fc2_b = (const float*)d_in[12];
  const float* fc3_W = (const float*)d_in[13], *fc3_b = (const float*)d_in[14];
  const float* nn1_W = (const float*)d_in[15], *nn1_b = (const float*)d_in[16];
  const float* nn2_W = (const float*)d_in[17], *nn2_b = (const float*)d_in[18];
  const float* cl4_W = (const float*)d_in[19], *cl4_b = (const float*)d_in[20];
  const float* fcg1_W = (const float*)d_in[21], *fcg1_b = (const float*)d_in[22];
  const float* fcg2_W = (const float*)d_in[23], *fcg2_b = (const float*)d_in[24];
  const float* nn14_W = (const float*)d_in[25], *nn14_b = (const float*)d_in[26];
  const float* nn24_W = (const float*)d_in[27], *nn24_b = (const float*)d_in[28];
  const float* fcsum_W = (const float*)d_in[29], *fcsum_b = (const float*)d_in[30];

  char* ws = (char*)d_ws;
  int* rowptr = (int*)(ws + WS_ROWPTR);
  unsigned short* xin16 = (unsigned short*)(ws + WS_XIN16);
  float* T = (float*)(ws + WS_T);              // 6 planes of 2097152 floats
  unsigned short* xpool = (unsigned short*)(ws + WS_XPOOL);
  unsigned short* Xb0 = (unsigned short*)(ws + WS_XB0);
  unsigned short* Xb1 = (unsigned short*)(ws + WS_XB1);
  unsigned short* xnn1b = (unsigned short*)(ws + WS_XNN1B);
  unsigned short* dec2 = (unsigned short*)(ws + WS_DEC2);
  float* xnn2 = (float*)(ws + WS_XNN2);
  unsigned short* hidB = (unsigned short*)(ws + WS_HIDB);
  float* n1 = (float*)(ws + WS_N1);
  float* tail = (float*)(ws + WS_TAIL);
  float* pnn1 = (float*)(ws + WS_PNN1);
  float* pfc1 = (float*)(ws + WS_PFC1);

  float* out0 = (float*)d_out;                 // x_decode_gae [128,16384]
  float* hidden = out0 + 2097152;              // x_hidden_gae [128,512]
  float* logp = out0 + 2097152 + 65536;        // [128,10]

  // L1: g4 + nn14 + prep + transpose
  setup_kernel<<<4161, 256, 0, stream>>>(x_in, L_rows, rowptr, xin16, T, Xb0,
                                         x_embed, nn14_W, nn14_b, n1,
                                         L_mg, cl4_W, cl4_b, fcg1_W, fcg1_b,
                                         fcg2_W, fcg2_b, tail);

  // L2-L6: Chebyshev recursion (bf16 gather source, fp32 state)
  spmm3<<<4096, 256, 0, stream>>>(rowptr, L_cols, L_vals, (const unsigned*)Xb0,
                                  nullptr,          T + 1 * 2097152, (unsigned*)Xb1, 1.f);
  spmm3<<<4096, 256, 0, stream>>>(rowptr, L_cols, L_vals, (const unsigned*)Xb1,
                                  T,                T + 2 * 2097152, (unsigned*)Xb0, 2.f);
  spmm3<<<4096, 256, 0, stream>>>(rowptr, L_cols, L_vals, (const unsigned*)Xb0,
                                  T + 1 * 2097152,  T + 3 * 2097152, (unsigned*)Xb1, 2.f);
  spmm3<<<4096, 256, 0, stream>>>(rowptr, L_cols, L_vals, (const unsigned*)Xb1,
                                  T + 2 * 2097152,  T + 4 * 2097152, (unsigned*)Xb0, 2.f);
  spmm3<<<4096, 256, 0, stream>>>(rowptr, L_cols, L_vals, (const unsigned*)Xb0,
                                  T + 3 * 2097152,  T + 5 * 2097152, (unsigned*)Xb1, 2.f);

  // L7: combine+pool (+nn24)
  combine_nn24<<<2064, 256, 0, stream>>>(T, cl1_W, cl1_b, xpool,
                                         n1, nn24_W, nn24_b, tail + 64);

  // L8: nn1 (256) + fc1 (1024) split-K partials, Kchunk=256
  gemm_partials<<<1280, 256, 0, stream>>>(xin16, nn1_W, xpool, fc1_W, pnn1, pfc1);

  // L9: fused reduce -> hidden(+bf16), xnn1b
  reduce_fused<<<512, 256, 0, stream>>>(pfc1, fc1_b, hidden, hidB,
                                        pnn1, nn1_b, xnn1b);

  // L10: fc2 -> dec2 (bf16), nn2 -> xnn2 (fp32)
  fc2nn2_kernel<<<12, 256, 0, stream>>>(hidB, fc2_W, fc2_b, dec2,
                                        xnn1b, nn2_W, nn2_b, xnn2);

  // L11: fc3 -> x_decode_gae (M-split x4) + fcsum/log_softmax -> logp
  fc3_head<<<1056, 256, 0, stream>>>(dec2, fc3_W, fc3_b, out0,
                                     hidden, xnn2, tail, fcsum_W, fcsum_b, logp);
}

// Round 9
// 284.891 us; speedup vs baseline: 1.1131x; 1.1131x over previous
//
#include <hip/hip_runtime.h>
#include <hip/hip_bf16.h>

#define DG 16384
#define NNZ 262144
#define BB 128

typedef __attribute__((ext_vector_type(8))) short bf16x8;
typedef __attribute__((ext_vector_type(8))) unsigned short us8;
typedef __attribute__((ext_vector_type(4))) float f32x4;
typedef __attribute__((ext_vector_type(4))) unsigned short us4;
typedef __attribute__((ext_vector_type(2))) float f32x2;

// ---- workspace layout (bytes) ----
#define WS_ROWPTR 0            // 16385 ints
#define WS_XIN16  66048        // 128*16384 bf16
#define WS_T      4260352      // 6 fp32 planes of 16384*128
#define WS_XPOOL  54592000     // 128*65536 bf16
#define WS_XB0    71369216     // bf16 shadow plane A
#define WS_XB1    75563520     // bf16 shadow plane B
#define WS_XNN1B  79757824     // 128*512 bf16
#define WS_DEC2   79888896     // 128*512 bf16
#define WS_XNN2   80019968     // 128*256 fp32
#define WS_HIDB   80151040     // 128*512 bf16
#define WS_N1     80282112     // 256*4
#define WS_TAIL   80283136     // 128*4
#define WS_PNN1   81000448     // 32 planes * 256KB = 8.4MB
#define WS_PFC1   97777664     // 128 planes * 256KB = 33.5MB (ends ~131MB)

__device__ __forceinline__ unsigned short f2bf(float f) {
  __hip_bfloat16 h = __float2bfloat16(f);
  return __builtin_bit_cast(unsigned short, h);
}
__device__ __forceinline__ float bflo(unsigned u) {
  return __builtin_bit_cast(float, u << 16);
}
__device__ __forceinline__ float bfhi(unsigned u) {
  return __builtin_bit_cast(float, u & 0xffff0000u);
}
__device__ __forceinline__ f32x4 ntload4(const float* p) {
  return __builtin_nontemporal_load((const f32x4*)p);
}

// ================= fused setup: g4 | nn14 | prep | transpose =================
__device__ void prep_dev(const float* __restrict__ x_in, const int* __restrict__ rows,
                         int* __restrict__ rowptr, unsigned short* __restrict__ xin16,
                         int bid) {
  int idx = bid * 256 + threadIdx.x;
  if (idx <= DG) {
    int lo = 0, hi = NNZ;
    while (lo < hi) { int mid = (lo + hi) >> 1; if (rows[mid] < idx) lo = mid + 1; else hi = mid; }
    rowptr[idx] = lo;
  }
  f32x4 v = ((const f32x4*)x_in)[idx];
  us4 o; o[0] = f2bf(v[0]); o[1] = f2bf(v[1]); o[2] = f2bf(v[2]); o[3] = f2bf(v[3]);
  ((us4*)xin16)[idx] = o;
}

__device__ void transpose_dev(const float* __restrict__ x_in, float* __restrict__ T0,
                              unsigned short* __restrict__ Xb0, int id) {
  __shared__ float tl[32][33];
  int bx = id & 511, by = id >> 9;
  int v0 = bx * 32, b0 = by * 32;
  int tx = threadIdx.x & 31, ty0 = threadIdx.x >> 5;
  #pragma unroll
  for (int j = 0; j < 4; ++j) {
    int ty = ty0 + j * 8;
    tl[ty][tx] = x_in[(size_t)(b0 + ty) * DG + v0 + tx];
  }
  __syncthreads();
  #pragma unroll
  for (int j = 0; j < 4; ++j) {
    int ty = ty0 + j * 8;
    float v = tl[tx][ty];
    size_t o = (size_t)(v0 + ty) * BB + b0 + tx;
    T0[o] = v;
    Xb0[o] = f2bf(v);
  }
}

__device__ void dot4_dev(const float* __restrict__ x, const float* __restrict__ W,
                         const float* __restrict__ bias, float* __restrict__ out,
                         int K, int id) {
  int w = threadIdx.x >> 6, lane = threadIdx.x & 63;
  int o = id * 4 + w;
  float a = 0.f;
  for (int i = lane; i < K; i += 64) a += x[i] * W[(size_t)o * K + i];
  #pragma unroll
  for (int s = 32; s > 0; s >>= 1) a += __shfl_down(a, s);
  if (lane == 0) out[o] = fmaxf(a + bias[o], 0.f);
}

__device__ void g4_dev(const float* __restrict__ xe_g, const float* __restrict__ Lmg_g,
                       const float* __restrict__ W4, const float* __restrict__ b4,
                       const float* __restrict__ Wg1, const float* __restrict__ bg1,
                       const float* __restrict__ Wg2, const float* __restrict__ bg2,
                       float* __restrict__ tail) {
  __shared__ float Lm[100], Tg[4][640], xc[320], xg96[96], h1[128];
  int t = threadIdx.x;
  for (int i = t; i < 640; i += 256) Tg[0][i] = xe_g[i];
  for (int i = t; i < 100; i += 256) Lm[i] = Lmg_g[i];
  __syncthreads();
  for (int i = t; i < 640; i += 256) {
    int v = i >> 6, f = i & 63; float s = 0.f;
    #pragma unroll
    for (int u = 0; u < 10; ++u) s += Lm[v * 10 + u] * Tg[0][u * 64 + f];
    Tg[1][i] = s;
  }
  __syncthreads();
  for (int kk = 2; kk < 4; ++kk) {
    for (int i = t; i < 640; i += 256) {
      int v = i >> 6, f = i & 63; float s = 0.f;
      #pragma unroll
      for (int u = 0; u < 10; ++u) s += Lm[v * 10 + u] * Tg[kk - 1][u * 64 + f];
      Tg[kk][i] = 2.f * s - Tg[kk - 2][i];
    }
    __syncthreads();
  }
  for (int i = t; i < 320; i += 256) {
    int v = i >> 5, fo = i & 31; float s = b4[fo];
    for (int fin = 0; fin < 64; ++fin)
      #pragma unroll
      for (int k = 0; k < 4; ++k) s += Tg[k][v * 64 + fin] * W4[fo * 256 + fin * 4 + k];
    xc[i] = fmaxf(s, 0.f);
  }
  __syncthreads();
  for (int i = t; i < 96; i += 256) {
    int g = i >> 5, fo = i & 31;
    xg96[i] = fmaxf(fmaxf(xc[(3 * g) * 32 + fo], xc[(3 * g + 1) * 32 + fo]),
                    xc[(3 * g + 2) * 32 + fo]);
  }
  __syncthreads();
  for (int o = t; o < 128; o += 256) {
    float s = bg1[o];
    for (int i2 = 0; i2 < 96; ++i2) s += xg96[i2] * Wg1[o * 96 + i2];
    h1[o] = fmaxf(s, 0.f);
  }
  __syncthreads();
  for (int o = t; o < 64; o += 256) {
    float s = bg2[o];
    for (int i2 = 0; i2 < 128; ++i2) s += h1[i2] * Wg2[o * 128 + i2];
    tail[o] = fmaxf(s, 0.f);
  }
}

__global__ __launch_bounds__(256) void setup_kernel(
    const float* __restrict__ x_in, const int* __restrict__ rows,
    int* __restrict__ rowptr, unsigned short* __restrict__ xin16,
    float* __restrict__ T0, unsigned short* __restrict__ Xb0,
    const float* __restrict__ x_embed,
    const float* __restrict__ nn14_W, const float* __restrict__ nn14_b,
    float* __restrict__ n1,
    const float* __restrict__ Lmg, const float* __restrict__ W4,
    const float* __restrict__ b4, const float* __restrict__ Wg1,
    const float* __restrict__ bg1, const float* __restrict__ Wg2,
    const float* __restrict__ bg2, float* __restrict__ tail) {
  int bid = blockIdx.x;
  if (bid < 1) g4_dev(x_embed, Lmg, W4, b4, Wg1, bg1, Wg2, bg2, tail);
  else if (bid < 65) dot4_dev(x_embed, nn14_W, nn14_b, n1, 640, bid - 1);
  else if (bid < 2113) prep_dev(x_in, rows, rowptr, xin16, bid - 65);
  else transpose_dev(x_in, T0, Xb0, bid - 2113);
}

// ====== SpMM: 1 wave/row, ushort2 gathers, Chebyshev update (R4-proven) ======
__global__ __launch_bounds__(256) void spmm3(
    const int* __restrict__ rowptr, const int* __restrict__ cols,
    const float* __restrict__ vals, const unsigned* __restrict__ X2,
    const float* __restrict__ Tprev, float* __restrict__ Tout,
    unsigned* __restrict__ Xbout, float scale) {
  int r = blockIdx.x * 4 + (threadIdx.x >> 6);
  int lane = threadIdx.x & 63;
  int e0 = rowptr[r], e1 = rowptr[r + 1];
  float a00 = 0.f, a01 = 0.f, a10 = 0.f, a11 = 0.f;
  int e = e0;
  for (; e + 4 <= e1; e += 4) {
    int c0 = cols[e], c1 = cols[e + 1], c2 = cols[e + 2], c3 = cols[e + 3];
    float v0 = vals[e], v1 = vals[e + 1], v2 = vals[e + 2], v3 = vals[e + 3];
    unsigned x0 = X2[c0 * 64 + lane], x1 = X2[c1 * 64 + lane];
    unsigned x2 = X2[c2 * 64 + lane], x3 = X2[c3 * 64 + lane];
    a00 += v0 * bflo(x0); a10 += v0 * bfhi(x0);
    a01 += v1 * bflo(x1); a11 += v1 * bfhi(x1);
    a00 += v2 * bflo(x2); a10 += v2 * bfhi(x2);
    a01 += v3 * bflo(x3); a11 += v3 * bfhi(x3);
  }
  for (; e < e1; ++e) {
    float v = vals[e]; unsigned x = X2[cols[e] * 64 + lane];
    a00 += v * bflo(x); a10 += v * bfhi(x);
  }
  float s0 = scale * (a00 + a01), s1 = scale * (a10 + a11);
  size_t o = (size_t)r * BB + lane * 2;
  if (Tprev) { f32x2 p = *(const f32x2*)(Tprev + o); s0 -= p[0]; s1 -= p[1]; }
  *(f32x2*)(Tout + o) = (f32x2){s0, s1};
  Xbout[(size_t)r * 64 + lane] = (unsigned)f2bf(s0) | ((unsigned)f2bf(s1) << 16);
}

// ====== combine + maxpool (+ nn24 piggyback) ======
__device__ void combine_dev(const float* __restrict__ Tbase, const float* __restrict__ W,
                            const float* __restrict__ bias, unsigned short* __restrict__ xpool,
                            int vp) {
  __shared__ float tile[6][8][128];
  __shared__ float Wl[192];
  __shared__ float bl[32];
  for (int i = threadIdx.x; i < 192; i += 256) Wl[i] = W[i];
  if (threadIdx.x < 32) bl[threadIdx.x] = bias[threadIdx.x];
  for (int i = threadIdx.x; i < 6144; i += 256) {
    int k = i >> 10, rem = i & 1023, j = rem >> 7, b = rem & 127;
    tile[k][j][b] = Tbase[(size_t)k * 2097152 + (size_t)(vp * 8 + j) * BB + b];
  }
  __syncthreads();
  for (int p = threadIdx.x; p < 4096; p += 256) {
    int b = p >> 5, f = p & 31;
    float m = -1e30f;
    #pragma unroll
    for (int j = 0; j < 8; ++j) {
      float s = bl[f];
      #pragma unroll
      for (int k = 0; k < 6; ++k) s += tile[k][j][b] * Wl[f * 6 + k];
      m = fmaxf(m, s);
    }
    m = fmaxf(m, 0.f);
    xpool[(size_t)b * 65536 + vp * 32 + f] = f2bf(m);
  }
}

__global__ __launch_bounds__(256) void combine_nn24(
    const float* __restrict__ Tbase, const float* __restrict__ W,
    const float* __restrict__ bias, unsigned short* __restrict__ xpool,
    const float* __restrict__ n1, const float* __restrict__ nn24_W,
    const float* __restrict__ nn24_b, float* __restrict__ tail64) {
  int bid = blockIdx.x;
  if (bid < 2048) combine_dev(Tbase, W, bias, xpool, bid);
  else dot4_dev(n1, nn24_W, nn24_b, tail64, 256, bid - 2048);
}

// ====== MFMA GEMM core v5: A via XOR-swizzled LDS (shared by waves),
//        W fragments DIRECT global->reg (no cross-wave reuse) ======
template<int NT, int MT>
__device__ void gemm_core5(
    unsigned short* __restrict__ Alds,       // [MT*16 * 64] bf16
    const unsigned short* __restrict__ A, const float* __restrict__ W,
    float* __restrict__ outP, unsigned short* __restrict__ outB,
    const float* __restrict__ bias, int K, int N, int Kchunk,
    int bx, int by, int row0, int relu, int partial) {
  const int LA = MT / 2;        // us8 loads per thread for A tile (MT*16 rows x 64k)
  int t = threadIdx.x, w = t >> 6, lane = t & 63, lr = lane & 15, lg = lane >> 4;
  int n0 = bx * NT * 64;
  int kbeg = by * Kchunk;
  f32x4 acc[MT][NT];
  #pragma unroll
  for (int mt = 0; mt < MT; ++mt)
    #pragma unroll
    for (int nt = 0; nt < NT; ++nt) acc[mt][nt] = (f32x4){0.f, 0.f, 0.f, 0.f};
  const float* Wbase = W + (size_t)(n0 + w * NT * 16 + lr) * K + lg * 8;
  int stages = Kchunk >> 6;
  for (int s = 0; s < stages; ++s) {
    int k0 = kbeg + s * 64;
    // W fragment loads: issue early, latency hides under barrier/other waves' MFMA
    f32x4 rw[NT][4];
    #pragma unroll
    for (int nt = 0; nt < NT; ++nt) {
      const float* wp = Wbase + (size_t)nt * 16 * K + k0;
      rw[nt][0] = ntload4(wp);      rw[nt][1] = ntload4(wp + 4);
      rw[nt][2] = ntload4(wp + 32); rw[nt][3] = ntload4(wp + 36);
    }
    __syncthreads();                         // previous stage's A readers done
    #pragma unroll
    for (int j = 0; j < LA; ++j) {
      int idx = j * 256 + t;
      int row = idx >> 3, kk = (idx & 7) * 8;
      us8 v = *(const us8*)(A + (size_t)(row0 + row) * K + k0 + kk);
      *(us8*)(Alds + row * 64 + (kk ^ ((row & 7) << 3))) = v;
    }
    __syncthreads();                         // A tile ready
    #pragma unroll
    for (int h = 0; h < 2; ++h) {
      int k32 = h * 32;
      bf16x8 bfr[NT];
      #pragma unroll
      for (int nt = 0; nt < NT; ++nt) {
        f32x4 w0 = rw[nt][h * 2], w1 = rw[nt][h * 2 + 1];
        bf16x8 bv;
        bv[0] = (short)f2bf(w0[0]); bv[1] = (short)f2bf(w0[1]);
        bv[2] = (short)f2bf(w0[2]); bv[3] = (short)f2bf(w0[3]);
        bv[4] = (short)f2bf(w1[0]); bv[5] = (short)f2bf(w1[1]);
        bv[6] = (short)f2bf(w1[2]); bv[7] = (short)f2bf(w1[3]);
        bfr[nt] = bv;
      }
      #pragma unroll
      for (int mt = 0; mt < MT; ++mt) {
        int arow = mt * 16 + lr;
        bf16x8 af = *(const bf16x8*)(Alds + arow * 64 + ((k32 + lg * 8) ^ ((arow & 7) << 3)));
        #pragma unroll
        for (int nt = 0; nt < NT; ++nt)
          acc[mt][nt] = __builtin_amdgcn_mfma_f32_16x16x32_bf16(af, bfr[nt], acc[mt][nt], 0, 0, 0);
      }
    }
  }
  if (partial) {
    float* P = outP + (size_t)by * 128 * (size_t)N;
    #pragma unroll
    for (int mt = 0; mt < MT; ++mt)
      #pragma unroll
      for (int nt = 0; nt < NT; ++nt) {
        int col = n0 + w * NT * 16 + nt * 16 + lr;
        #pragma unroll
        for (int r2 = 0; r2 < 4; ++r2) {
          int row = row0 + mt * 16 + lg * 4 + r2;
          P[(size_t)row * N + col] = acc[mt][nt][r2];
        }
      }
  } else {
    #pragma unroll
    for (int mt = 0; mt < MT; ++mt)
      #pragma unroll
      for (int nt = 0; nt < NT; ++nt) {
        int col = n0 + w * NT * 16 + nt * 16 + lr;
        float bc = bias[col];
        #pragma unroll
        for (int r2 = 0; r2 < 4; ++r2) {
          int row = row0 + mt * 16 + lg * 4 + r2;
          float v = acc[mt][nt][r2] + bc;
          if (relu) v = fmaxf(v, 0.f);
          if (outP) outP[(size_t)row * N + col] = v;
          if (outB) outB[(size_t)row * N + col] = f2bf(v);
        }
      }
  }
}

// ====== fused nn1+fc1 split-K partial gemm (Kchunk=512, XCD-swizzled) ======
__global__ __launch_bounds__(256, 4) void gemm_partials(
    const unsigned short* __restrict__ xin16, const float* __restrict__ nn1_W,
    const unsigned short* __restrict__ xpool, const float* __restrict__ fc1_W,
    float* __restrict__ pnn1, float* __restrict__ pfc1) {
  __shared__ unsigned short Alds[128 * 64];
  int nb = blockIdx.x;
  if (nb < 128) {
    int xcd = nb & 7, q = nb >> 3, bx = q & 3, by = ((q >> 2) << 3) | xcd;
    gemm_core5<2, 8>(Alds, xin16, nn1_W, pnn1, nullptr, nullptr,
                     16384, 512, 512, bx, by, 0, 0, 1);
  } else {
    int b = nb - 128;
    int xcd = b & 7, q = b >> 3, bx = q & 3, by = ((q >> 2) << 3) | xcd;
    gemm_core5<2, 8>(Alds, xpool, fc1_W, pfc1, nullptr, nullptr,
                     65536, 512, 512, bx, by, 0, 0, 1);
  }
}

// ====== fused split-K reduce: fc1 (S=128) + nn1 (S=32) ======
__global__ __launch_bounds__(256) void reduce_fused(
    const float* __restrict__ pfc1, const float* __restrict__ fc1_b,
    float* __restrict__ hidden, unsigned short* __restrict__ hidB,
    const float* __restrict__ pnn1, const float* __restrict__ nn1_b,
    unsigned short* __restrict__ xnn1b) {
  int b = blockIdx.x;
  if (b < 256) {
    int idx = b * 256 + threadIdx.x;
    float s = 0.f;
    for (int i = 0; i < 128; ++i) s += pfc1[(size_t)i * 65536 + idx];
    float v = fmaxf(s + fc1_b[idx & 511], 0.f);
    hidden[idx] = v;
    hidB[idx] = f2bf(v);
  } else {
    int idx = (b - 256) * 256 + threadIdx.x;
    float s = 0.f;
    for (int i = 0; i < 32; ++i) s += pnn1[(size_t)i * 65536 + idx];
    float v = fmaxf(s + nn1_b[idx & 511], 0.f);
    xnn1b[idx] = f2bf(v);
  }
}

// ====== fc2 + nn2 fused ======
__global__ __launch_bounds__(256, 4) void fc2nn2_kernel(
    const unsigned short* __restrict__ hidB, const float* __restrict__ fc2_W,
    const float* __restrict__ fc2_b, unsigned short* __restrict__ dec2,
    const unsigned short* __restrict__ xnn1b, const float* __restrict__ nn2_W,
    const float* __restrict__ nn2_b, float* __restrict__ xnn2) {
  __shared__ unsigned short Alds[128 * 64];
  int b = blockIdx.x;
  if (b < 8)
    gemm_core5<1, 8>(Alds, hidB, fc2_W, nullptr, dec2, fc2_b,
                     512, 512, 512, b, 0, 0, 1, 0);
  else
    gemm_core5<1, 8>(Alds, xnn1b, nn2_W, xnn2, nullptr, nn2_b,
                     512, 256, 512, b - 8, 0, 0, 1, 0);
}

// ====== fc3 (M-split x2) + fcsum head ======
__device__ void fcsum_dev(int id, const float* __restrict__ hidden,
                          const float* __restrict__ xnn2, const float* __restrict__ tail,
                          const float* __restrict__ Ws, const float* __restrict__ bs,
                          float* __restrict__ logp) {
  __shared__ float emb[4][896];
  int w = threadIdx.x >> 6, lane = threadIdx.x & 63;
  int b = id * 4 + w;
  for (int i = lane; i < 896; i += 64)
    emb[w][i] = (i < 512) ? hidden[b * 512 + i]
              : (i < 768) ? xnn2[b * 256 + (i - 512)]
                          : tail[i - 768];
  __syncthreads();
  float l[10];
  #pragma unroll
  for (int o = 0; o < 10; ++o) {
    float a = 0.f;
    for (int i = lane; i < 896; i += 64) a += emb[w][i] * Ws[o * 896 + i];
    #pragma unroll
    for (int s = 32; s > 0; s >>= 1) a += __shfl_down(a, s);
    l[o] = __shfl(a, 0) + bs[o];
  }
  float m = l[0];
  #pragma unroll
  for (int o = 1; o < 10; ++o) m = fmaxf(m, l[o]);
  float sum = 0.f;
  #pragma unroll
  for (int o = 0; o < 10; ++o) sum += expf(l[o] - m);
  float lse = m + logf(sum);
  #pragma unroll
  for (int o = 0; o < 10; ++o)
    if (lane == o) logp[b * 10 + o] = l[o] - lse;
}

__global__ __launch_bounds__(256, 4) void fc3_head(
    const unsigned short* __restrict__ dec2, const float* __restrict__ fc3_W,
    const float* __restrict__ fc3_b, float* __restrict__ out0,
    const float* __restrict__ hidden, const float* __restrict__ xnn2,
    const float* __restrict__ tail, const float* __restrict__ fcsum_W,
    const float* __restrict__ fcsum_b, float* __restrict__ logp) {
  __shared__ unsigned short Alds[64 * 64];
  int b = blockIdx.x;
  if (b < 512) {
    int bx = b >> 1, my = b & 1;
    gemm_core5<1, 4>(Alds, dec2, fc3_W, out0, nullptr, fc3_b,
                     512, 16384, 512, bx, 0, my * 64, 0, 0);
  } else {
    fcsum_dev(b - 512, hidden, xnn2, tail, fcsum_W, fcsum_b, logp);
  }
}

extern "C" void kernel_launch(void* const* d_in, const int* in_sizes, int n_in,
                              void* d_out, int out_size, void* d_ws, size_t ws_size,
                              hipStream_t stream) {
  const float* x_in    = (const float*)d_in[0];
  const float* x_embed = (const float*)d_in[1];
  const int*   L_rows  = (const int*)d_in[3];
  const int*   L_cols  = (const int*)d_in[4];
  const float* L_vals  = (const float*)d_in[5];
  const float* L_mg    = (const float*)d_in[6];
  const float* cl1_W = (const float*)d_in[7],  *cl1_b = (const float*)d_in[8];
  const float* fc1_W = (const float*)d_in[9],  *fc1_b = (const float*)d_in[10];
  const float* fc2_W = (const float*)d_in[11], *fc2_b = (const float*)d_in[12];
  const float* fc3_W = (const float*)d_in[13], *fc3_b = (const float*)d_in[14];
  const float* nn1_W = (const float*)d_in[15], *nn1_b = (const float*)d_in[16];
  const float* nn2_W = (const float*)d_in[17], *nn2_b = (const float*)d_in[18];
  const float* cl4_W = (const float*)d_in[19], *cl4_b = (const float*)d_in[20];
  const float* fcg1_W = (const float*)d_in[21], *fcg1_b = (const float*)d_in[22];
  const float* fcg2_W = (const float*)d_in[23], *fcg2_b = (const float*)d_in[24];
  const float* nn14_W = (const float*)d_in[25], *nn14_b = (const float*)d_in[26];
  const float* nn24_W = (const float*)d_in[27], *nn24_b = (const float*)d_in[28];
  const float* fcsum_W = (const float*)d_in[29], *fcsum_b = (const float*)d_in[30];

  char* ws = (char*)d_ws;
  int* rowptr = (int*)(ws + WS_ROWPTR);
  unsigned short* xin16 = (unsigned short*)(ws + WS_XIN16);
  float* T = (float*)(ws + WS_T);              // 6 planes of 2097152 floats
  unsigned short* xpool = (unsigned short*)(ws + WS_XPOOL);
  unsigned short* Xb0 = (unsigned short*)(ws + WS_XB0);
  unsigned short* Xb1 = (unsigned short*)(ws + WS_XB1);
  unsigned short* xnn1b = (unsigned short*)(ws + WS_XNN1B);
  unsigned short* dec2 = (unsigned short*)(ws + WS_DEC2);
  float* xnn2 = (float*)(ws + WS_XNN2);
  unsigned short* hidB = (unsigned short*)(ws + WS_HIDB);
  float* n1 = (float*)(ws + WS_N1);
  float* tail = (float*)(ws + WS_TAIL);
  float* pnn1 = (float*)(ws + WS_PNN1);
  float* pfc1 = (float*)(ws + WS_PFC1);

  float* out0 = (float*)d_out;                 // x_decode_gae [128,16384]
  float* hidden = out0 + 2097152;              // x_hidden_gae [128,512]
  float* logp = out0 + 2097152 + 65536;        // [128,10]

  // L1: g4 + nn14 + prep + transpose
  setup_kernel<<<4161, 256, 0, stream>>>(x_in, L_rows, rowptr, xin16, T, Xb0,
                                         x_embed, nn14_W, nn14_b, n1,
                                         L_mg, cl4_W, cl4_b, fcg1_W, fcg1_b,
                                         fcg2_W, fcg2_b, tail);

  // L2-L6: Chebyshev recursion (bf16 gather source, fp32 state)
  spmm3<<<4096, 256, 0, stream>>>(rowptr, L_cols, L_vals, (const unsigned*)Xb0,
                                  nullptr,          T + 1 * 2097152, (unsigned*)Xb1, 1.f);
  spmm3<<<4096, 256, 0, stream>>>(rowptr, L_cols, L_vals, (const unsigned*)Xb1,
                                  T,                T + 2 * 2097152, (unsigned*)Xb0, 2.f);
  spmm3<<<4096, 256, 0, stream>>>(rowptr, L_cols, L_vals, (const unsigned*)Xb0,
                                  T + 1 * 2097152,  T + 3 * 2097152, (unsigned*)Xb1, 2.f);
  spmm3<<<4096, 256, 0, stream>>>(rowptr, L_cols, L_vals, (const unsigned*)Xb1,
                                  T + 2 * 2097152,  T + 4 * 2097152, (unsigned*)Xb0, 2.f);
  spmm3<<<4096, 256, 0, stream>>>(rowptr, L_cols, L_vals, (const unsigned*)Xb0,
                                  T + 3 * 2097152,  T + 5 * 2097152, (unsigned*)Xb1, 2.f);

  // L7: combine+pool (+nn24)
  combine_nn24<<<2064, 256, 0, stream>>>(T, cl1_W, cl1_b, xpool,
                                         n1, nn24_W, nn24_b, tail + 64);

  // L8: nn1 (128) + fc1 (512) split-K partials, W direct-to-fragment
  gemm_partials<<<640, 256, 0, stream>>>(xin16, nn1_W, xpool, fc1_W, pnn1, pfc1);

  // L9: fused reduce -> hidden(+bf16), xnn1b
  reduce_fused<<<512, 256, 0, stream>>>(pfc1, fc1_b, hidden, hidB,
                                        pnn1, nn1_b, xnn1b);

  // L10: fc2 -> dec2 (bf16), nn2 -> xnn2 (fp32)
  fc2nn2_kernel<<<12, 256, 0, stream>>>(hidB, fc2_W, fc2_b, dec2,
                                        xnn1b, nn2_W, nn2_b, xnn2);

  // L11: fc3 -> x_decode_gae (M-split x2) + fcsum/log_softmax -> logp
  fc3_head<<<544, 256, 0, stream>>>(dec2, fc3_W, fc3_b, out0,
                                    hidden, xnn2, tail, fcsum_W, fcsum_b, logp);
}

// Round 10
// 267.324 us; speedup vs baseline: 1.1862x; 1.0657x over previous
//
#include <hip/hip_runtime.h>
#include <hip/hip_bf16.h>

#define DG 16384
#define NNZ 262144
#define BB 128

typedef __attribute__((ext_vector_type(8))) short bf16x8;
typedef __attribute__((ext_vector_type(8))) unsigned short us8;
typedef __attribute__((ext_vector_type(4))) float f32x4;
typedef __attribute__((ext_vector_type(4))) unsigned short us4;
typedef __attribute__((ext_vector_type(2))) float f32x2;

// ---- workspace layout (bytes) ----
#define WS_ROWPTR 0            // 16385 ints
#define WS_XIN16  66048        // 128*16384 bf16
#define WS_T      4260352      // 6 fp32 planes of 16384*128
#define WS_XPOOL  54592000     // 128*65536 bf16
#define WS_XB0    71369216     // bf16 shadow plane A
#define WS_XB1    75563520     // bf16 shadow plane B
#define WS_XNN1B  79757824     // 128*512 bf16
#define WS_DEC2   79888896     // 128*512 bf16
#define WS_XNN2   80019968     // 128*256 fp32
#define WS_HIDB   80151040     // 128*512 bf16
#define WS_N1     80282112     // 256*4
#define WS_TAIL   80283136     // 128*4
#define WS_PNN1   81000448     // 32 planes * 256KB = 8.4MB
#define WS_PFC1   97777664     // 128 planes * 256KB = 33.5MB (ends ~131MB)

__device__ __forceinline__ unsigned short f2bf(float f) {
  __hip_bfloat16 h = __float2bfloat16(f);
  return __builtin_bit_cast(unsigned short, h);
}
__device__ __forceinline__ float bflo(unsigned u) {
  return __builtin_bit_cast(float, u << 16);
}
__device__ __forceinline__ float bfhi(unsigned u) {
  return __builtin_bit_cast(float, u & 0xffff0000u);
}
__device__ __forceinline__ f32x4 ntload4(const float* p) {
  return __builtin_nontemporal_load((const f32x4*)p);
}

// ================= fused setup: g4 | nn14 | prep | transpose =================
__device__ void prep_dev(const float* __restrict__ x_in, const int* __restrict__ rows,
                         int* __restrict__ rowptr, unsigned short* __restrict__ xin16,
                         int bid) {
  int idx = bid * 256 + threadIdx.x;
  if (idx <= DG) {
    int lo = 0, hi = NNZ;
    while (lo < hi) { int mid = (lo + hi) >> 1; if (rows[mid] < idx) lo = mid + 1; else hi = mid; }
    rowptr[idx] = lo;
  }
  f32x4 v = ((const f32x4*)x_in)[idx];
  us4 o; o[0] = f2bf(v[0]); o[1] = f2bf(v[1]); o[2] = f2bf(v[2]); o[3] = f2bf(v[3]);
  ((us4*)xin16)[idx] = o;
}

__device__ void transpose_dev(const float* __restrict__ x_in, float* __restrict__ T0,
                              unsigned short* __restrict__ Xb0, int id) {
  __shared__ float tl[32][33];
  int bx = id & 511, by = id >> 9;
  int v0 = bx * 32, b0 = by * 32;
  int tx = threadIdx.x & 31, ty0 = threadIdx.x >> 5;
  #pragma unroll
  for (int j = 0; j < 4; ++j) {
    int ty = ty0 + j * 8;
    tl[ty][tx] = x_in[(size_t)(b0 + ty) * DG + v0 + tx];
  }
  __syncthreads();
  #pragma unroll
  for (int j = 0; j < 4; ++j) {
    int ty = ty0 + j * 8;
    float v = tl[tx][ty];
    size_t o = (size_t)(v0 + ty) * BB + b0 + tx;
    T0[o] = v;
    Xb0[o] = f2bf(v);
  }
}

__device__ void dot4_dev(const float* __restrict__ x, const float* __restrict__ W,
                         const float* __restrict__ bias, float* __restrict__ out,
                         int K, int id) {
  int w = threadIdx.x >> 6, lane = threadIdx.x & 63;
  int o = id * 4 + w;
  float a = 0.f;
  for (int i = lane; i < K; i += 64) a += x[i] * W[(size_t)o * K + i];
  #pragma unroll
  for (int s = 32; s > 0; s >>= 1) a += __shfl_down(a, s);
  if (lane == 0) out[o] = fmaxf(a + bias[o], 0.f);
}

__device__ void g4_dev(const float* __restrict__ xe_g, const float* __restrict__ Lmg_g,
                       const float* __restrict__ W4, const float* __restrict__ b4,
                       const float* __restrict__ Wg1, const float* __restrict__ bg1,
                       const float* __restrict__ Wg2, const float* __restrict__ bg2,
                       float* __restrict__ tail) {
  __shared__ float Lm[100], Tg[4][640], xc[320], xg96[96], h1[128];
  int t = threadIdx.x;
  for (int i = t; i < 640; i += 256) Tg[0][i] = xe_g[i];
  for (int i = t; i < 100; i += 256) Lm[i] = Lmg_g[i];
  __syncthreads();
  for (int i = t; i < 640; i += 256) {
    int v = i >> 6, f = i & 63; float s = 0.f;
    #pragma unroll
    for (int u = 0; u < 10; ++u) s += Lm[v * 10 + u] * Tg[0][u * 64 + f];
    Tg[1][i] = s;
  }
  __syncthreads();
  for (int kk = 2; kk < 4; ++kk) {
    for (int i = t; i < 640; i += 256) {
      int v = i >> 6, f = i & 63; float s = 0.f;
      #pragma unroll
      for (int u = 0; u < 10; ++u) s += Lm[v * 10 + u] * Tg[kk - 1][u * 64 + f];
      Tg[kk][i] = 2.f * s - Tg[kk - 2][i];
    }
    __syncthreads();
  }
  for (int i = t; i < 320; i += 256) {
    int v = i >> 5, fo = i & 31; float s = b4[fo];
    for (int fin = 0; fin < 64; ++fin)
      #pragma unroll
      for (int k = 0; k < 4; ++k) s += Tg[k][v * 64 + fin] * W4[fo * 256 + fin * 4 + k];
    xc[i] = fmaxf(s, 0.f);
  }
  __syncthreads();
  for (int i = t; i < 96; i += 256) {
    int g = i >> 5, fo = i & 31;
    xg96[i] = fmaxf(fmaxf(xc[(3 * g) * 32 + fo], xc[(3 * g + 1) * 32 + fo]),
                    xc[(3 * g + 2) * 32 + fo]);
  }
  __syncthreads();
  for (int o = t; o < 128; o += 256) {
    float s = bg1[o];
    for (int i2 = 0; i2 < 96; ++i2) s += xg96[i2] * Wg1[o * 96 + i2];
    h1[o] = fmaxf(s, 0.f);
  }
  __syncthreads();
  for (int o = t; o < 64; o += 256) {
    float s = bg2[o];
    for (int i2 = 0; i2 < 128; ++i2) s += h1[i2] * Wg2[o * 128 + i2];
    tail[o] = fmaxf(s, 0.f);
  }
}

__global__ __launch_bounds__(256) void setup_kernel(
    const float* __restrict__ x_in, const int* __restrict__ rows,
    int* __restrict__ rowptr, unsigned short* __restrict__ xin16,
    float* __restrict__ T0, unsigned short* __restrict__ Xb0,
    const float* __restrict__ x_embed,
    const float* __restrict__ nn14_W, const float* __restrict__ nn14_b,
    float* __restrict__ n1,
    const float* __restrict__ Lmg, const float* __restrict__ W4,
    const float* __restrict__ b4, const float* __restrict__ Wg1,
    const float* __restrict__ bg1, const float* __restrict__ Wg2,
    const float* __restrict__ bg2, float* __restrict__ tail) {
  int bid = blockIdx.x;
  if (bid < 1) g4_dev(x_embed, Lmg, W4, b4, Wg1, bg1, Wg2, bg2, tail);
  else if (bid < 65) dot4_dev(x_embed, nn14_W, nn14_b, n1, 640, bid - 1);
  else if (bid < 2113) prep_dev(x_in, rows, rowptr, xin16, bid - 65);
  else transpose_dev(x_in, T0, Xb0, bid - 2113);
}

// ====== SpMM: 1 wave/row, ushort2 gathers, Chebyshev update (R4-proven) ======
__global__ __launch_bounds__(256) void spmm3(
    const int* __restrict__ rowptr, const int* __restrict__ cols,
    const float* __restrict__ vals, const unsigned* __restrict__ X2,
    const float* __restrict__ Tprev, float* __restrict__ Tout,
    unsigned* __restrict__ Xbout, float scale) {
  int r = blockIdx.x * 4 + (threadIdx.x >> 6);
  int lane = threadIdx.x & 63;
  int e0 = rowptr[r], e1 = rowptr[r + 1];
  float a00 = 0.f, a01 = 0.f, a10 = 0.f, a11 = 0.f;
  int e = e0;
  for (; e + 4 <= e1; e += 4) {
    int c0 = cols[e], c1 = cols[e + 1], c2 = cols[e + 2], c3 = cols[e + 3];
    float v0 = vals[e], v1 = vals[e + 1], v2 = vals[e + 2], v3 = vals[e + 3];
    unsigned x0 = X2[c0 * 64 + lane], x1 = X2[c1 * 64 + lane];
    unsigned x2 = X2[c2 * 64 + lane], x3 = X2[c3 * 64 + lane];
    a00 += v0 * bflo(x0); a10 += v0 * bfhi(x0);
    a01 += v1 * bflo(x1); a11 += v1 * bfhi(x1);
    a00 += v2 * bflo(x2); a10 += v2 * bfhi(x2);
    a01 += v3 * bflo(x3); a11 += v3 * bfhi(x3);
  }
  for (; e < e1; ++e) {
    float v = vals[e]; unsigned x = X2[cols[e] * 64 + lane];
    a00 += v * bflo(x); a10 += v * bfhi(x);
  }
  float s0 = scale * (a00 + a01), s1 = scale * (a10 + a11);
  size_t o = (size_t)r * BB + lane * 2;
  if (Tprev) { f32x2 p = *(const f32x2*)(Tprev + o); s0 -= p[0]; s1 -= p[1]; }
  *(f32x2*)(Tout + o) = (f32x2){s0, s1};
  Xbout[(size_t)r * 64 + lane] = (unsigned)f2bf(s0) | ((unsigned)f2bf(s1) << 16);
}

// ====== combine + maxpool (+ nn24 piggyback) ======
__device__ void combine_dev(const float* __restrict__ Tbase, const float* __restrict__ W,
                            const float* __restrict__ bias, unsigned short* __restrict__ xpool,
                            int vp) {
  __shared__ float tile[6][8][128];
  __shared__ float Wl[192];
  __shared__ float bl[32];
  for (int i = threadIdx.x; i < 192; i += 256) Wl[i] = W[i];
  if (threadIdx.x < 32) bl[threadIdx.x] = bias[threadIdx.x];
  for (int i = threadIdx.x; i < 6144; i += 256) {
    int k = i >> 10, rem = i & 1023, j = rem >> 7, b = rem & 127;
    tile[k][j][b] = Tbase[(size_t)k * 2097152 + (size_t)(vp * 8 + j) * BB + b];
  }
  __syncthreads();
  for (int p = threadIdx.x; p < 4096; p += 256) {
    int b = p >> 5, f = p & 31;
    float m = -1e30f;
    #pragma unroll
    for (int j = 0; j < 8; ++j) {
      float s = bl[f];
      #pragma unroll
      for (int k = 0; k < 6; ++k) s += tile[k][j][b] * Wl[f * 6 + k];
      m = fmaxf(m, s);
    }
    m = fmaxf(m, 0.f);
    xpool[(size_t)b * 65536 + vp * 32 + f] = f2bf(m);
  }
}

__global__ __launch_bounds__(256) void combine_nn24(
    const float* __restrict__ Tbase, const float* __restrict__ W,
    const float* __restrict__ bias, unsigned short* __restrict__ xpool,
    const float* __restrict__ n1, const float* __restrict__ nn24_W,
    const float* __restrict__ nn24_b, float* __restrict__ tail64) {
  int bid = blockIdx.x;
  if (bid < 2048) combine_dev(Tbase, W, bias, xpool, bid);
  else dot4_dev(n1, nn24_W, nn24_b, tail64, 256, bid - 2048);
}

// ====== R4's LDS-staged MFMA GEMM core (serialized staging, MT=8) ======
template<int NT>
__device__ void gemm_core(
    unsigned short* __restrict__ Alds,       // [128 * 64]
    unsigned short* __restrict__ Wlds,       // [NT*64 * 64]
    const unsigned short* __restrict__ A, const float* __restrict__ W,
    float* __restrict__ outP, unsigned short* __restrict__ outB,
    const float* __restrict__ bias, int K, int N, int Kchunk,
    int bx, int by, int relu, int partial) {
  int t = threadIdx.x, w = t >> 6, lane = t & 63, lr = lane & 15, lg = lane >> 4;
  int n0 = bx * NT * 64;
  int kbeg = by * Kchunk;
  f32x4 acc[8][NT];
  #pragma unroll
  for (int mt = 0; mt < 8; ++mt)
    #pragma unroll
    for (int nt = 0; nt < NT; ++nt) acc[mt][nt] = (f32x4){0.f, 0.f, 0.f, 0.f};
  int stages = Kchunk >> 6;
  for (int s = 0; s < stages; ++s) {
    int k0 = kbeg + s * 64;
    __syncthreads();                         // previous stage's readers done
    #pragma unroll
    for (int j = 0; j < 4; ++j) {
      int idx = j * 256 + t;
      int row = idx >> 3, kk = (idx & 7) * 8;
      us8 v = *(const us8*)(A + (size_t)row * K + k0 + kk);
      *(us8*)(Alds + row * 64 + (kk ^ ((row & 7) << 3))) = v;
    }
    #pragma unroll
    for (int j = 0; j < NT * 4; ++j) {
      int idx = j * 256 + t;
      int wr = idx >> 4, kk = (idx & 15) * 4;
      f32x4 v = *(const f32x4*)(W + (size_t)(n0 + wr) * K + k0 + kk);
      us4 o; o[0] = f2bf(v[0]); o[1] = f2bf(v[1]); o[2] = f2bf(v[2]); o[3] = f2bf(v[3]);
      *(us4*)(Wlds + wr * 64 + (kk ^ ((wr & 7) << 3))) = o;
    }
    __syncthreads();                         // LDS tile ready
    #pragma unroll
    for (int h = 0; h < 2; ++h) {
      int k32 = h * 32;
      bf16x8 bfr[NT];
      #pragma unroll
      for (int nt = 0; nt < NT; ++nt) {
        int wrow = w * NT * 16 + nt * 16 + lr;
        bfr[nt] = *(const bf16x8*)(Wlds + wrow * 64 + ((k32 + lg * 8) ^ ((wrow & 7) << 3)));
      }
      #pragma unroll
      for (int mt = 0; mt < 8; ++mt) {
        int arow = mt * 16 + lr;
        bf16x8 af = *(const bf16x8*)(Alds + arow * 64 + ((k32 + lg * 8) ^ ((arow & 7) << 3)));
        #pragma unroll
        for (int nt = 0; nt < NT; ++nt)
          acc[mt][nt] = __builtin_amdgcn_mfma_f32_16x16x32_bf16(af, bfr[nt], acc[mt][nt], 0, 0, 0);
      }
    }
  }
  if (partial) {
    float* P = outP + (size_t)by * 128 * (size_t)N;
    #pragma unroll
    for (int mt = 0; mt < 8; ++mt)
      #pragma unroll
      for (int nt = 0; nt < NT; ++nt) {
        int col = n0 + w * NT * 16 + nt * 16 + lr;
        #pragma unroll
        for (int r2 = 0; r2 < 4; ++r2) {
          int row = mt * 16 + lg * 4 + r2;
          P[(size_t)row * N + col] = acc[mt][nt][r2];
        }
      }
  } else {
    #pragma unroll
    for (int mt = 0; mt < 8; ++mt)
      #pragma unroll
      for (int nt = 0; nt < NT; ++nt) {
        int col = n0 + w * NT * 16 + nt * 16 + lr;
        float bc = bias[col];
        #pragma unroll
        for (int r2 = 0; r2 < 4; ++r2) {
          int row = mt * 16 + lg * 4 + r2;
          float v = acc[mt][nt][r2] + bc;
          if (relu) v = fmaxf(v, 0.f);
          if (outP) outP[(size_t)row * N + col] = v;
          if (outB) outB[(size_t)row * N + col] = f2bf(v);
        }
      }
  }
}

// ====== R9's MFMA GEMM core v5: A via XOR-swizzled LDS, W direct global->reg ======
template<int NT, int MT>
__device__ void gemm_core5(
    unsigned short* __restrict__ Alds,       // [MT*16 * 64] bf16
    const unsigned short* __restrict__ A, const float* __restrict__ W,
    float* __restrict__ outP, unsigned short* __restrict__ outB,
    const float* __restrict__ bias, int K, int N, int Kchunk,
    int bx, int by, int row0, int relu, int partial) {
  const int LA = MT / 2;
  int t = threadIdx.x, w = t >> 6, lane = t & 63, lr = lane & 15, lg = lane >> 4;
  int n0 = bx * NT * 64;
  int kbeg = by * Kchunk;
  f32x4 acc[MT][NT];
  #pragma unroll
  for (int mt = 0; mt < MT; ++mt)
    #pragma unroll
    for (int nt = 0; nt < NT; ++nt) acc[mt][nt] = (f32x4){0.f, 0.f, 0.f, 0.f};
  const float* Wbase = W + (size_t)(n0 + w * NT * 16 + lr) * K + lg * 8;
  int stages = Kchunk >> 6;
  for (int s = 0; s < stages; ++s) {
    int k0 = kbeg + s * 64;
    f32x4 rw[NT][4];
    #pragma unroll
    for (int nt = 0; nt < NT; ++nt) {
      const float* wp = Wbase + (size_t)nt * 16 * K + k0;
      rw[nt][0] = ntload4(wp);      rw[nt][1] = ntload4(wp + 4);
      rw[nt][2] = ntload4(wp + 32); rw[nt][3] = ntload4(wp + 36);
    }
    __syncthreads();
    #pragma unroll
    for (int j = 0; j < LA; ++j) {
      int idx = j * 256 + t;
      int row = idx >> 3, kk = (idx & 7) * 8;
      us8 v = *(const us8*)(A + (size_t)(row0 + row) * K + k0 + kk);
      *(us8*)(Alds + row * 64 + (kk ^ ((row & 7) << 3))) = v;
    }
    __syncthreads();
    #pragma unroll
    for (int h = 0; h < 2; ++h) {
      int k32 = h * 32;
      bf16x8 bfr[NT];
      #pragma unroll
      for (int nt = 0; nt < NT; ++nt) {
        f32x4 w0 = rw[nt][h * 2], w1 = rw[nt][h * 2 + 1];
        bf16x8 bv;
        bv[0] = (short)f2bf(w0[0]); bv[1] = (short)f2bf(w0[1]);
        bv[2] = (short)f2bf(w0[2]); bv[3] = (short)f2bf(w0[3]);
        bv[4] = (short)f2bf(w1[0]); bv[5] = (short)f2bf(w1[1]);
        bv[6] = (short)f2bf(w1[2]); bv[7] = (short)f2bf(w1[3]);
        bfr[nt] = bv;
      }
      #pragma unroll
      for (int mt = 0; mt < MT; ++mt) {
        int arow = mt * 16 + lr;
        bf16x8 af = *(const bf16x8*)(Alds + arow * 64 + ((k32 + lg * 8) ^ ((arow & 7) << 3)));
        #pragma unroll
        for (int nt = 0; nt < NT; ++nt)
          acc[mt][nt] = __builtin_amdgcn_mfma_f32_16x16x32_bf16(af, bfr[nt], acc[mt][nt], 0, 0, 0);
      }
    }
  }
  if (partial) {
    float* P = outP + (size_t)by * 128 * (size_t)N;
    #pragma unroll
    for (int mt = 0; mt < MT; ++mt)
      #pragma unroll
      for (int nt = 0; nt < NT; ++nt) {
        int col = n0 + w * NT * 16 + nt * 16 + lr;
        #pragma unroll
        for (int r2 = 0; r2 < 4; ++r2) {
          int row = row0 + mt * 16 + lg * 4 + r2;
          P[(size_t)row * N + col] = acc[mt][nt][r2];
        }
      }
  } else {
    #pragma unroll
    for (int mt = 0; mt < MT; ++mt)
      #pragma unroll
      for (int nt = 0; nt < NT; ++nt) {
        int col = n0 + w * NT * 16 + nt * 16 + lr;
        float bc = bias[col];
        #pragma unroll
        for (int r2 = 0; r2 < 4; ++r2) {
          int row = row0 + mt * 16 + lg * 4 + r2;
          float v = acc[mt][nt][r2] + bc;
          if (relu) v = fmaxf(v, 0.f);
          if (outP) outP[(size_t)row * N + col] = v;
          if (outB) outB[(size_t)row * N + col] = f2bf(v);
        }
      }
  }
}

// ====== fused nn1+fc1 split-K partial gemm (R9-proven: core5, W direct) ======
__global__ __launch_bounds__(256, 4) void gemm_partials(
    const unsigned short* __restrict__ xin16, const float* __restrict__ nn1_W,
    const unsigned short* __restrict__ xpool, const float* __restrict__ fc1_W,
    float* __restrict__ pnn1, float* __restrict__ pfc1) {
  __shared__ unsigned short Alds[128 * 64];
  int nb = blockIdx.x;
  if (nb < 128) {
    int xcd = nb & 7, q = nb >> 3, bx = q & 3, by = ((q >> 2) << 3) | xcd;
    gemm_core5<2, 8>(Alds, xin16, nn1_W, pnn1, nullptr, nullptr,
                     16384, 512, 512, bx, by, 0, 0, 1);
  } else {
    int b = nb - 128;
    int xcd = b & 7, q = b >> 3, bx = q & 3, by = ((q >> 2) << 3) | xcd;
    gemm_core5<2, 8>(Alds, xpool, fc1_W, pfc1, nullptr, nullptr,
                     65536, 512, 512, bx, by, 0, 0, 1);
  }
}

// ====== fused split-K reduce: fc1 (S=128) + nn1 (S=32) ======
__global__ __launch_bounds__(256) void reduce_fused(
    const float* __restrict__ pfc1, const float* __restrict__ fc1_b,
    float* __restrict__ hidden, unsigned short* __restrict__ hidB,
    const float* __restrict__ pnn1, const float* __restrict__ nn1_b,
    unsigned short* __restrict__ xnn1b) {
  int b = blockIdx.x;
  if (b < 256) {
    int idx = b * 256 + threadIdx.x;
    float s = 0.f;
    for (int i = 0; i < 128; ++i) s += pfc1[(size_t)i * 65536 + idx];
    float v = fmaxf(s + fc1_b[idx & 511], 0.f);
    hidden[idx] = v;
    hidB[idx] = f2bf(v);
  } else {
    int idx = (b - 256) * 256 + threadIdx.x;
    float s = 0.f;
    for (int i = 0; i < 32; ++i) s += pnn1[(size_t)i * 65536 + idx];
    float v = fmaxf(s + nn1_b[idx & 511], 0.f);
    xnn1b[idx] = f2bf(v);
  }
}

// ====== fc2 + nn2 fused (R4-proven) ======
__global__ __launch_bounds__(256) void fc2nn2_kernel(
    const unsigned short* __restrict__ hidB, const float* __restrict__ fc2_W,
    const float* __restrict__ fc2_b, unsigned short* __restrict__ dec2,
    const unsigned short* __restrict__ xnn1b, const float* __restrict__ nn2_W,
    const float* __restrict__ nn2_b, float* __restrict__ xnn2) {
  __shared__ unsigned short Alds[128 * 64];
  __shared__ unsigned short Wlds[64 * 64];
  int b = blockIdx.x;
  if (b < 8)
    gemm_core<1>(Alds, Wlds, hidB, fc2_W, nullptr, dec2, fc2_b,
                 512, 512, 512, b, 0, 1, 0);
  else
    gemm_core<1>(Alds, Wlds, xnn1b, nn2_W, xnn2, nullptr, nn2_b,
                 512, 256, 512, b - 8, 0, 1, 0);
}

// ====== fc3 + fcsum head (R4-proven) ======
__device__ void fcsum_dev(int id, const float* __restrict__ hidden,
                          const float* __restrict__ xnn2, const float* __restrict__ tail,
                          const float* __restrict__ Ws, const float* __restrict__ bs,
                          float* __restrict__ logp) {
  __shared__ float emb[4][896];
  int w = threadIdx.x >> 6, lane = threadIdx.x & 63;
  int b = id * 4 + w;
  for (int i = lane; i < 896; i += 64)
    emb[w][i] = (i < 512) ? hidden[b * 512 + i]
              : (i < 768) ? xnn2[b * 256 + (i - 512)]
                          : tail[i - 768];
  __syncthreads();
  float l[10];
  #pragma unroll
  for (int o = 0; o < 10; ++o) {
    float a = 0.f;
    for (int i = lane; i < 896; i += 64) a += emb[w][i] * Ws[o * 896 + i];
    #pragma unroll
    for (int s = 32; s > 0; s >>= 1) a += __shfl_down(a, s);
    l[o] = __shfl(a, 0) + bs[o];
  }
  float m = l[0];
  #pragma unroll
  for (int o = 1; o < 10; ++o) m = fmaxf(m, l[o]);
  float sum = 0.f;
  #pragma unroll
  for (int o = 0; o < 10; ++o) sum += expf(l[o] - m);
  float lse = m + logf(sum);
  #pragma unroll
  for (int o = 0; o < 10; ++o)
    if (lane == o) logp[b * 10 + o] = l[o] - lse;
}

__global__ __launch_bounds__(256) void fc3_head(
    const unsigned short* __restrict__ dec2, const float* __restrict__ fc3_W,
    const float* __restrict__ fc3_b, float* __restrict__ out0,
    const float* __restrict__ hidden, const float* __restrict__ xnn2,
    const float* __restrict__ tail, const float* __restrict__ fcsum_W,
    const float* __restrict__ fcsum_b, float* __restrict__ logp) {
  __shared__ unsigned short Alds[128 * 64];
  __shared__ unsigned short Wlds[64 * 64];
  int b = blockIdx.x;
  if (b < 256)
    gemm_core<1>(Alds, Wlds, dec2, fc3_W, out0, nullptr, fc3_b,
                 512, 16384, 512, b, 0, 0, 0);
  else
    fcsum_dev(b - 256, hidden, xnn2, tail, fcsum_W, fcsum_b, logp);
}

extern "C" void kernel_launch(void* const* d_in, const int* in_sizes, int n_in,
                              void* d_out, int out_size, void* d_ws, size_t ws_size,
                              hipStream_t stream) {
  const float* x_in    = (const float*)d_in[0];
  const float* x_embed = (const float*)d_in[1];
  const int*   L_rows  = (const int*)d_in[3];
  const int*   L_cols  = (const int*)d_in[4];
  const float* L_vals  = (const float*)d_in[5];
  const float* L_mg    = (const float*)d_in[6];
  const float* cl1_W = (const float*)d_in[7],  *cl1_b = (const float*)d_in[8];
  const float* fc1_W = (const float*)d_in[9],  *fc1_b = (const float*)d_in[10];
  const float* fc2_W = (const float*)d_in[11], *fc2_b = (const float*)d_in[12];
  const float* fc3_W = (const float*)d_in[13], *fc3_b = (const float*)d_in[14];
  const float* nn1_W = (const float*)d_in[15], *nn1_b = (const float*)d_in[16];
  const float* nn2_W = (const float*)d_in[17], *nn2_b = (const float*)d_in[18];
  const float* cl4_W = (const float*)d_in[19], *cl4_b = (const float*)d_in[20];
  const float* fcg1_W = (const float*)d_in[21], *fcg1_b = (const float*)d_in[22];
  const float* fcg2_W = (const float*)d_in[23], *fcg2_b = (const float*)d_in[24];
  const float* nn14_W = (const float*)d_in[25], *nn14_b = (const float*)d_in[26];
  const float* nn24_W = (const float*)d_in[27], *nn24_b = (const float*)d_in[28];
  const float* fcsum_W = (const float*)d_in[29], *fcsum_b = (const float*)d_in[30];

  char* ws = (char*)d_ws;
  int* rowptr = (int*)(ws + WS_ROWPTR);
  unsigned short* xin16 = (unsigned short*)(ws + WS_XIN16);
  float* T = (float*)(ws + WS_T);              // 6 planes of 2097152 floats
  unsigned short* xpool = (unsigned short*)(ws + WS_XPOOL);
  unsigned short* Xb0 = (unsigned short*)(ws + WS_XB0);
  unsigned short* Xb1 = (unsigned short*)(ws + WS_XB1);
  unsigned short* xnn1b = (unsigned short*)(ws + WS_XNN1B);
  unsigned short* dec2 = (unsigned short*)(ws + WS_DEC2);
  float* xnn2 = (float*)(ws + WS_XNN2);
  unsigned short* hidB = (unsigned short*)(ws + WS_HIDB);
  float* n1 = (float*)(ws + WS_N1);
  float* tail = (float*)(ws + WS_TAIL);
  float* pnn1 = (float*)(ws + WS_PNN1);
  float* pfc1 = (float*)(ws + WS_PFC1);

  float* out0 = (float*)d_out;                 // x_decode_gae [128,16384]
  float* hidden = out0 + 2097152;              // x_hidden_gae [128,512]
  float* logp = out0 + 2097152 + 65536;        // [128,10]

  // L1: g4 + nn14 + prep + transpose
  setup_kernel<<<4161, 256, 0, stream>>>(x_in, L_rows, rowptr, xin16, T, Xb0,
                                         x_embed, nn14_W, nn14_b, n1,
                                         L_mg, cl4_W, cl4_b, fcg1_W, fcg1_b,
                                         fcg2_W, fcg2_b, tail);

  // L2-L6: Chebyshev recursion (bf16 gather source, fp32 state)
  spmm3<<<4096, 256, 0, stream>>>(rowptr, L_cols, L_vals, (const unsigned*)Xb0,
                                  nullptr,          T + 1 * 2097152, (unsigned*)Xb1, 1.f);
  spmm3<<<4096, 256, 0, stream>>>(rowptr, L_cols, L_vals, (const unsigned*)Xb1,
                                  T,                T + 2 * 2097152, (unsigned*)Xb0, 2.f);
  spmm3<<<4096, 256, 0, stream>>>(rowptr, L_cols, L_vals, (const unsigned*)Xb0,
                                  T + 1 * 2097152,  T + 3 * 2097152, (unsigned*)Xb1, 2.f);
  spmm3<<<4096, 256, 0, stream>>>(rowptr, L_cols, L_vals, (const unsigned*)Xb1,
                                  T + 2 * 2097152,  T + 4 * 2097152, (unsigned*)Xb0, 2.f);
  spmm3<<<4096, 256, 0, stream>>>(rowptr, L_cols, L_vals, (const unsigned*)Xb0,
                                  T + 3 * 2097152,  T + 5 * 2097152, (unsigned*)Xb1, 2.f);

  // L7: combine+pool (+nn24)
  combine_nn24<<<2064, 256, 0, stream>>>(T, cl1_W, cl1_b, xpool,
                                         n1, nn24_W, nn24_b, tail + 64);

  // L8: nn1 (128) + fc1 (512) split-K partials, W direct-to-fragment (R9 version)
  gemm_partials<<<640, 256, 0, stream>>>(xin16, nn1_W, xpool, fc1_W, pnn1, pfc1);

  // L9: fused reduce -> hidden(+bf16), xnn1b
  reduce_fused<<<512, 256, 0, stream>>>(pfc1, fc1_b, hidden, hidB,
                                        pnn1, nn1_b, xnn1b);

  // L10: fc2 -> dec2 (bf16), nn2 -> xnn2 (fp32)  [R4 version]
  fc2nn2_kernel<<<12, 256, 0, stream>>>(hidB, fc2_W, fc2_b, dec2,
                                        xnn1b, nn2_W, nn2_b, xnn2);

  // L11: fc3 -> x_decode_gae + fcsum/log_softmax -> logp  [R4 version]
  fc3_head<<<288, 256, 0, stream>>>(dec2, fc3_W, fc3_b, out0,
                                    hidden, xnn2, tail, fcsum_W, fcsum_b, logp);
}